// Round 1
// baseline (145.217 us; speedup 1.0000x reference)
//
#include <hip/hip_runtime.h>
#include <math.h>

#define BB 8
#define HH 256
#define KK 256
#define EE 128

// One block per (b,h). 256 threads = 4 waves.
__global__ __launch_bounds__(256) void kvmn_main(
    const float* __restrict__ hidden,     // [B,H,E]
    const float* __restrict__ key_emb,    // [VOCAB,E]
    const float* __restrict__ value_emb,  // [FVOCAB,E]
    const int*   __restrict__ key_seq,    // [B,K]
    const int*   __restrict__ value_seq,  // [B,H,K]
    const int*   __restrict__ mask,       // [B,H,K]
    float* __restrict__ sum_ws,           // [B,E] atomic accum
    int*   __restrict__ cnt_ws)           // [B,E] nonzero counts
{
    __shared__ int    sh_ks[KK];
    __shared__ int    sh_vs[KK];
    __shared__ float  sh_u[KK];      // u, then p
    __shared__ float  sh_wsum[4];
    __shared__ float2 sh_o2[4][64];

    const int bid  = blockIdx.x;
    const int b    = bid >> 8;       // / HH
    const int h    = bid & 255;      // % HH
    const int tid  = threadIdx.x;
    const int w    = tid >> 6;       // wave id 0..3
    const int lane = tid & 63;

    // stage gather indices (coalesced)
    sh_ks[tid] = key_seq[b * KK + tid];
    sh_vs[tid] = value_seq[(b * HH + h) * KK + tid];

    // per-lane hidden fragment: e = 2*lane, 2*lane+1
    const float2 h2 = *(const float2*)&hidden[(size_t)(b * HH + h) * EE + lane * 2];

    __syncthreads();

    const float inv_scale = 0.08838834764831845f; // 1/sqrt(128)

    // ---- phase 1: u[k] = dot(hidden_row, key_row)/sqrt(E), wave w handles k in [64w,64w+64)
    for (int i = 0; i < 64; ++i) {
        const int   k   = w * 64 + i;
        const int   row = sh_ks[k];
        const float2 kv = *(const float2*)&key_emb[(size_t)row * EE + lane * 2];
        float partial = h2.x * kv.x + h2.y * kv.y;
        #pragma unroll
        for (int off = 32; off > 0; off >>= 1)
            partial += __shfl_down(partial, off, 64);
        if (lane == 0) sh_u[k] = partial * inv_scale;
    }
    __syncthreads();

    // ---- phase 2: delta = exp(u)*mask; denom; p = delta/(denom+1e-10)
    const float d = expf(sh_u[tid]) * (float)mask[(b * HH + h) * KK + tid];
    float wsum = d;
    #pragma unroll
    for (int off = 32; off > 0; off >>= 1)
        wsum += __shfl_down(wsum, off, 64);
    if (lane == 0) sh_wsum[w] = wsum;
    __syncthreads();
    const float denom = sh_wsum[0] + sh_wsum[1] + sh_wsum[2] + sh_wsum[3];
    const float inv   = 1.0f / (denom + 1e-10f);
    sh_u[tid] = d * inv;   // safe: every thread already consumed its sh_u[tid]
    __syncthreads();

    // ---- phase 3: o[e] = sum_k p[k]*value_emb[vs[k]][e]; wave w handles k in [64w,64w+64)
    float2 acc = make_float2(0.f, 0.f);
    for (int i = 0; i < 64; ++i) {
        const int    k   = w * 64 + i;
        const float  p   = sh_u[k];
        const int    row = sh_vs[k];
        const float2 v   = *(const float2*)&value_emb[(size_t)row * EE + lane * 2];
        acc.x += p * v.x;
        acc.y += p * v.y;
    }
    sh_o2[w][lane] = acc;
    __syncthreads();

    // ---- combine 4 wave partials, emit atomics for cross-h reduction
    if (tid < 64) {
        const float2 r0 = sh_o2[0][tid];
        const float2 r1 = sh_o2[1][tid];
        const float2 r2 = sh_o2[2][tid];
        const float2 r3 = sh_o2[3][tid];
        const float ox = r0.x + r1.x + r2.x + r3.x;
        const float oy = r0.y + r1.y + r2.y + r3.y;
        const int e0 = tid * 2, e1 = tid * 2 + 1;
        atomicAdd(&sum_ws[b * EE + e0], ox);
        atomicAdd(&sum_ws[b * EE + e1], oy);
        if (ox != 0.0f) atomicAdd(&cnt_ws[b * EE + e0], 1);
        if (oy != 0.0f) atomicAdd(&cnt_ws[b * EE + e1], 1);
    }
}

__global__ __launch_bounds__(256) void kvmn_final(
    const float* __restrict__ sum_ws,
    const int*   __restrict__ cnt_ws,
    float* __restrict__ out)
{
    const int i = blockIdx.x * blockDim.x + threadIdx.x;
    if (i < BB * EE) out[i] = sum_ws[i] / (float)cnt_ws[i];
}

extern "C" void kernel_launch(void* const* d_in, const int* in_sizes, int n_in,
                              void* d_out, int out_size, void* d_ws, size_t ws_size,
                              hipStream_t stream) {
    const float* hidden    = (const float*)d_in[0];
    const float* key_emb   = (const float*)d_in[1];
    const float* value_emb = (const float*)d_in[2];
    const int*   key_seq   = (const int*)d_in[3];
    const int*   value_seq = (const int*)d_in[4];
    const int*   mask      = (const int*)d_in[5];

    float* sum_ws = (float*)d_ws;
    int*   cnt_ws = (int*)((char*)d_ws + BB * EE * sizeof(float));

    // zero the accumulators (ws is poisoned 0xAA before every launch)
    hipMemsetAsync(d_ws, 0, BB * EE * (sizeof(float) + sizeof(int)), stream);

    kvmn_main<<<BB * HH, 256, 0, stream>>>(hidden, key_emb, value_emb,
                                           key_seq, value_seq, mask,
                                           sum_ws, cnt_ws);
    kvmn_final<<<(BB * EE + 255) / 256, 256, 0, stream>>>(sum_ws, cnt_ws, (float*)d_out);
}

// Round 2
// 139.753 us; speedup vs baseline: 1.0391x; 1.0391x over previous
//
#include <hip/hip_runtime.h>
#include <math.h>

#define BB 8
#define HH 256
#define KK 256
#define EE 128

// One block per (b,h). 256 threads = 4 waves.
// Wave lane layout: half = lane>>5 (which of 2 rows this iter), sub = lane&31
// (covers e = sub*4 .. sub*4+3 as float4).
__global__ __launch_bounds__(256) void kvmn_main(
    const float* __restrict__ hidden,     // [B,H,E]
    const float* __restrict__ key_emb,    // [VOCAB,E]
    const float* __restrict__ value_emb,  // [FVOCAB,E]
    const int*   __restrict__ key_seq,    // [B,K]
    const int*   __restrict__ value_seq,  // [B,H,K]
    const int*   __restrict__ mask,       // [B,H,K]
    float* __restrict__ sum_ws,           // [B,E] atomic accum
    int*   __restrict__ cnt_ws)           // [B,E] nonzero counts
{
    __shared__ int    sh_ks[KK];
    __shared__ int    sh_vs[KK];
    __shared__ float  sh_p[KK];          // u, then p
    __shared__ float  sh_wsum[4];
    __shared__ float4 sh_o4[8][32];      // 4 KB: 8 partials (4 waves x 2 halves)

    const int bid  = blockIdx.x;
    const int b    = bid >> 8;           // / HH
    const int h    = bid & 255;          // % HH
    const int tid  = threadIdx.x;
    const int w    = tid >> 6;           // wave id 0..3
    const int lane = tid & 63;
    const int half = lane >> 5;          // 0/1: which row of the pair
    const int sub  = lane & 31;          // position within row (float4 granules)

    // stage gather indices + mask early (coalesced, overlaps latency)
    sh_ks[tid] = key_seq[b * KK + tid];
    sh_vs[tid] = value_seq[(b * HH + h) * KK + tid];
    const int my_mask = mask[(b * HH + h) * KK + tid];

    // per-lane hidden fragment for e = sub*4 .. sub*4+3 (same for both halves)
    const float4 h4 = *(const float4*)&hidden[(size_t)(b * HH + h) * EE + sub * 4];

    __syncthreads();

    const float inv_scale = 0.08838834764831845f; // 1/sqrt(128)

    // ---- phase 1: u[k] = dot(hidden_row, key_row)/sqrt(E)
    // wave w handles k in [64w, 64w+64); 2 k's per iteration (half 0/1)
    #pragma unroll 4
    for (int i = 0; i < 32; ++i) {
        const int    k   = w * 64 + i * 2 + half;
        const int    row = sh_ks[k];
        const float4 kv  = *(const float4*)&key_emb[(size_t)row * EE + sub * 4];
        float partial = kv.x * h4.x + kv.y * h4.y + kv.z * h4.z + kv.w * h4.w;
        // reduce over 32 lanes within each half (lane 0 and lane 32 get sums)
        partial += __shfl_down(partial, 16, 64);
        partial += __shfl_down(partial, 8, 64);
        partial += __shfl_down(partial, 4, 64);
        partial += __shfl_down(partial, 2, 64);
        partial += __shfl_down(partial, 1, 64);
        if (sub == 0) sh_p[k] = partial * inv_scale;
    }
    __syncthreads();

    // ---- phase 2: delta = exp(u)*mask; denom; p = delta/(denom+1e-10)
    const float d = expf(sh_p[tid]) * (float)my_mask;
    float wsum = d;
    #pragma unroll
    for (int off = 32; off > 0; off >>= 1)
        wsum += __shfl_down(wsum, off, 64);
    if (lane == 0) sh_wsum[w] = wsum;
    __syncthreads();
    const float denom = sh_wsum[0] + sh_wsum[1] + sh_wsum[2] + sh_wsum[3];
    const float inv   = 1.0f / (denom + 1e-10f);
    sh_p[tid] = d * inv;   // safe: each thread consumed only its own sh_p[tid]
    __syncthreads();

    // ---- phase 3: o[e] = sum_k p[k]*value_emb[vs[k]][e]; 2 k's per iteration
    float4 acc = make_float4(0.f, 0.f, 0.f, 0.f);
    #pragma unroll 4
    for (int i = 0; i < 32; ++i) {
        const int    k   = w * 64 + i * 2 + half;
        const float  p   = sh_p[k];
        const int    row = sh_vs[k];
        const float4 v   = *(const float4*)&value_emb[(size_t)row * EE + sub * 4];
        acc.x += p * v.x;
        acc.y += p * v.y;
        acc.z += p * v.z;
        acc.w += p * v.w;
    }
    sh_o4[w * 2 + half][sub] = acc;
    __syncthreads();

    // ---- combine 8 partials per e-chunk, emit atomics for cross-h reduction
    if (tid < 32) {
        float4 s = sh_o4[0][tid];
        #pragma unroll
        for (int r = 1; r < 8; ++r) {
            const float4 t = sh_o4[r][tid];
            s.x += t.x; s.y += t.y; s.z += t.z; s.w += t.w;
        }
        const int e0 = tid * 4;
        atomicAdd(&sum_ws[b * EE + e0 + 0], s.x);
        atomicAdd(&sum_ws[b * EE + e0 + 1], s.y);
        atomicAdd(&sum_ws[b * EE + e0 + 2], s.z);
        atomicAdd(&sum_ws[b * EE + e0 + 3], s.w);
        if (s.x != 0.0f) atomicAdd(&cnt_ws[b * EE + e0 + 0], 1);
        if (s.y != 0.0f) atomicAdd(&cnt_ws[b * EE + e0 + 1], 1);
        if (s.z != 0.0f) atomicAdd(&cnt_ws[b * EE + e0 + 2], 1);
        if (s.w != 0.0f) atomicAdd(&cnt_ws[b * EE + e0 + 3], 1);
    }
}

__global__ __launch_bounds__(256) void kvmn_final(
    const float* __restrict__ sum_ws,
    const int*   __restrict__ cnt_ws,
    float* __restrict__ out)
{
    const int i = blockIdx.x * blockDim.x + threadIdx.x;
    if (i < BB * EE) out[i] = sum_ws[i] / (float)cnt_ws[i];
}

extern "C" void kernel_launch(void* const* d_in, const int* in_sizes, int n_in,
                              void* d_out, int out_size, void* d_ws, size_t ws_size,
                              hipStream_t stream) {
    const float* hidden    = (const float*)d_in[0];
    const float* key_emb   = (const float*)d_in[1];
    const float* value_emb = (const float*)d_in[2];
    const int*   key_seq   = (const int*)d_in[3];
    const int*   value_seq = (const int*)d_in[4];
    const int*   mask      = (const int*)d_in[5];

    float* sum_ws = (float*)d_ws;
    int*   cnt_ws = (int*)((char*)d_ws + BB * EE * sizeof(float));

    hipMemsetAsync(d_ws, 0, BB * EE * (sizeof(float) + sizeof(int)), stream);

    kvmn_main<<<BB * HH, 256, 0, stream>>>(hidden, key_emb, value_emb,
                                           key_seq, value_seq, mask,
                                           sum_ws, cnt_ws);
    kvmn_final<<<(BB * EE + 255) / 256, 256, 0, stream>>>(sum_ws, cnt_ws, (float*)d_out);
}

// Round 3
// 105.577 us; speedup vs baseline: 1.3755x; 1.3237x over previous
//
#include <hip/hip_runtime.h>
#include <math.h>

#define BB 8
#define HH 256
#define KK 256
#define EE 128

// ---------------- Kernel A: one block per (b,h), 256 threads = 4 waves. ----------------
// Computes p[b,h,:] and o[b,h,:] and stores o to workspace (NO atomics).
__global__ __launch_bounds__(256) void kvmn_bh(
    const float* __restrict__ hidden,     // [B,H,E]
    const float* __restrict__ key_emb,    // [VOCAB,E]
    const float* __restrict__ value_emb,  // [FVOCAB,E]
    const int*   __restrict__ key_seq,    // [B,K]
    const int*   __restrict__ value_seq,  // [B,H,K]
    const int*   __restrict__ mask,       // [B,H,K]
    float* __restrict__ o_ws)             // [B,H,E]
{
    __shared__ int    sh_ks[KK];
    __shared__ int    sh_vs[KK];
    __shared__ float  sh_p[KK];          // u, then p
    __shared__ float  sh_wsum[4];
    __shared__ float4 sh_o4[8][32];      // 8 partials (4 waves x 2 halves)

    const int bid  = blockIdx.x;
    const int b    = bid >> 8;           // / HH
    const int h    = bid & 255;          // % HH
    const int tid  = threadIdx.x;
    const int w    = tid >> 6;           // wave id 0..3
    const int lane = tid & 63;
    const int half = lane >> 5;          // 0/1: which row of the pair
    const int sub  = lane & 31;          // float4 granule within row

    sh_ks[tid] = key_seq[b * KK + tid];
    sh_vs[tid] = value_seq[(b * HH + h) * KK + tid];
    const int my_mask = mask[(b * HH + h) * KK + tid];

    const float4 h4 = *(const float4*)&hidden[(size_t)(b * HH + h) * EE + sub * 4];

    __syncthreads();

    const float inv_scale = 0.08838834764831845f; // 1/sqrt(128)

    // ---- phase 1: u[k] = dot(hidden_row, key_row)/sqrt(E); 2 k's per iteration
    #pragma unroll 4
    for (int i = 0; i < 32; ++i) {
        const int    k   = w * 64 + i * 2 + half;
        const int    row = sh_ks[k];
        const float4 kv  = *(const float4*)&key_emb[(size_t)row * EE + sub * 4];
        float partial = kv.x * h4.x + kv.y * h4.y + kv.z * h4.z + kv.w * h4.w;
        partial += __shfl_down(partial, 16, 64);
        partial += __shfl_down(partial, 8, 64);
        partial += __shfl_down(partial, 4, 64);
        partial += __shfl_down(partial, 2, 64);
        partial += __shfl_down(partial, 1, 64);
        if (sub == 0) sh_p[k] = partial * inv_scale;
    }
    __syncthreads();

    // ---- phase 2: delta = exp(u)*mask; denom; p = delta/(denom+1e-10)
    const float d = expf(sh_p[tid]) * (float)my_mask;
    float wsum = d;
    #pragma unroll
    for (int off = 32; off > 0; off >>= 1)
        wsum += __shfl_down(wsum, off, 64);
    if (lane == 0) sh_wsum[w] = wsum;
    __syncthreads();
    const float denom = sh_wsum[0] + sh_wsum[1] + sh_wsum[2] + sh_wsum[3];
    const float inv   = 1.0f / (denom + 1e-10f);
    sh_p[tid] = d * inv;
    __syncthreads();

    // ---- phase 3: o[e] = sum_k p[k]*value_emb[vs[k]][e]; 2 k's per iteration
    float4 acc = make_float4(0.f, 0.f, 0.f, 0.f);
    #pragma unroll 4
    for (int i = 0; i < 32; ++i) {
        const int    k   = w * 64 + i * 2 + half;
        const float  p   = sh_p[k];
        const int    row = sh_vs[k];
        const float4 v   = *(const float4*)&value_emb[(size_t)row * EE + sub * 4];
        acc.x += p * v.x;
        acc.y += p * v.y;
        acc.z += p * v.z;
        acc.w += p * v.w;
    }
    sh_o4[w * 2 + half][sub] = acc;
    __syncthreads();

    // ---- combine 8 partials, plain store to workspace (coalesced, 512 B/block)
    if (tid < 32) {
        float4 s = sh_o4[0][tid];
        #pragma unroll
        for (int r = 1; r < 8; ++r) {
            const float4 t = sh_o4[r][tid];
            s.x += t.x; s.y += t.y; s.z += t.z; s.w += t.w;
        }
        *(float4*)&o_ws[(size_t)(b * HH + h) * EE + tid * 4] = s;
    }
}

// ---------------- Kernel B: reduce over H + nonzero-count average. ----------------
// One block per b; thread t covers e = t&127 over half the h range (hh = t>>7).
__global__ __launch_bounds__(256) void kvmn_reduce(
    const float* __restrict__ o_ws,      // [B,H,E]
    float* __restrict__ out)             // [B,E]
{
    __shared__ float sh_sum[256];
    __shared__ int   sh_cnt[256];

    const int b  = blockIdx.x;
    const int t  = threadIdx.x;
    const int e  = t & 127;
    const int hh = t >> 7;               // 0 or 1

    float sum = 0.0f;
    int   cnt = 0;
    const float* base = o_ws + (size_t)(b * HH + hh * 128) * EE + e;
    #pragma unroll 8
    for (int h = 0; h < 128; ++h) {
        const float v = base[(size_t)h * EE];
        sum += v;
        cnt += (v != 0.0f) ? 1 : 0;
    }
    sh_sum[t] = sum;
    sh_cnt[t] = cnt;
    __syncthreads();
    if (t < 128) {
        const float s = sh_sum[t] + sh_sum[t + 128];
        const int   c = sh_cnt[t] + sh_cnt[t + 128];
        out[b * EE + t] = s / (float)c;
    }
}

// ---------------- Fallback (atomic path) if ws is too small ----------------
__global__ __launch_bounds__(256) void kvmn_final_fb(
    const float* __restrict__ sum_ws, const int* __restrict__ cnt_ws,
    float* __restrict__ out)
{
    const int i = blockIdx.x * blockDim.x + threadIdx.x;
    if (i < BB * EE) out[i] = sum_ws[i] / (float)cnt_ws[i];
}

extern "C" void kernel_launch(void* const* d_in, const int* in_sizes, int n_in,
                              void* d_out, int out_size, void* d_ws, size_t ws_size,
                              hipStream_t stream) {
    const float* hidden    = (const float*)d_in[0];
    const float* key_emb   = (const float*)d_in[1];
    const float* value_emb = (const float*)d_in[2];
    const int*   key_seq   = (const int*)d_in[3];
    const int*   value_seq = (const int*)d_in[4];
    const int*   mask      = (const int*)d_in[5];

    const size_t need = (size_t)BB * HH * EE * sizeof(float);   // 1 MB
    float* o_ws = (float*)d_ws;

    // two-stage, atomic-free path
    kvmn_bh<<<BB * HH, 256, 0, stream>>>(hidden, key_emb, value_emb,
                                         key_seq, value_seq, mask, o_ws);
    kvmn_reduce<<<BB, 256, 0, stream>>>(o_ws, (float*)d_out);
    (void)need; (void)ws_size; (void)in_sizes; (void)n_in; (void)out_size;
}